// Round 1
// baseline (108.662 us; speedup 1.0000x reference)
//
#include <hip/hip_runtime.h>
#include <math.h>

#define BATCH 8
#define NPRED 8192
#define MPART 2048
#define NPTS  (BATCH * NPRED)      // 65536 queries
#define MTOT  (BATCH * MPART)      // 16384 partial points
#define QPL   4                    // queries per lane
#define SPLIT 16                   // 16 waves = 16 M-splits per block
#define PTS_PER_SPLIT (MPART / SPLIT)   // 128
#define GPS   (PTS_PER_SPLIT / 4)       // 32 groups of 4 points per split
#define QPB   256                  // queries per block (4 qpl * 64 lanes)
#define NBLK  (NPTS / QPB)         // 256 blocks
#define BLK_PER_B (NPRED / QPB)    // 32 blocks per batch
#define BASE_ALPHA 0.05f
#define EPS 1e-6f

typedef float fx16 __attribute__((ext_vector_type(16)));

// Grouped-SoA P': for each group g of 4 points, 16 consecutive floats:
//   [0..3]={-2x0..-2x3} [4..7]={-2y..} [8..11]={-2z..} [12..15]={|b|^2..}
// This is exactly one s_load_dwordx16 per group.
// near4[m] = (x,y,z,0) for the single-float4 nearest gather in updates.
__global__ __launch_bounds__(256) void prep_kernel(const float* __restrict__ partial,
                                                   float* __restrict__ ppgf,
                                                   float4* __restrict__ near4) {
    const int m = blockIdx.x * 256 + threadIdx.x;   // 64 blocks cover MTOT
    const float* p = partial + 3u * (unsigned)m;
    const float x = p[0], y = p[1], z = p[2];
    const int g = m >> 2, c = m & 3;
    float* base = ppgf + (size_t)g * 16 + c;
    base[0]  = -2.0f * x;
    base[4]  = -2.0f * y;
    base[8]  = -2.0f * z;
    base[12] = fmaf(x, x, fmaf(y, y, z * z));
    near4[m] = make_float4(x, y, z, 0.0f);
}

// Block = 1024 threads = 16 waves. Wave w scans M-split w (128 pts) for the
// block's 256 queries (4 per lane). The point tile is WAVE-UNIFORM, so it is
// read via s_load_dwordx16 into SGPRs (2 groups in flight) and consumed as
// the single SGPR operand of each VALU op — no LDS staging, no ds_reads, no
// staging barriers. LDS holds only the 32 KB cross-split key buffer.
// Grouped argmin: loop tracks (group-min, group-id) only; epilogue reloads the
// winning group from ppg (L2-resident, same bytes as the s_loads saw) and
// recomputes the 4 dots with IDENTICAL fp ops (bit-exact) to recover the
// element index; strict '<' + lowest-c tie-break = first-occurrence.
// FUSE: apply previous iteration's blend in the prologue.
template <bool FUSE>
__global__ __launch_bounds__(1024) void nn_kernel(
    const float* __restrict__ src,      // [B,N,3] base positions
    const float4* __restrict__ ppg,     // [MTOT] grouped-SoA P'
    const float4* __restrict__ near4,   // [MTOT] raw partial
    const float* md_in, const int* idx_in,   // FUSE only (may alias outputs)
    const float* __restrict__ bmax_in,  // [NBLK] per-block max from prev pass
    float* __restrict__ refined_out,    // [B,N,3] (FUSE)
    float* md_out, int* idx_out,        // [B*N]
    float* __restrict__ bmax_out)       // [NBLK]
{
    __shared__ unsigned long long lk[SPLIT * QPB];   // 32 KB key buffer
    __shared__ float smax[4];

    const int qb   = blockIdx.x;
    const int b    = qb >> 5;               // 32 blocks per batch
    const int tid  = threadIdx.x;
    const int wave = tid >> 6, lane = tid & 63;
    // Materialize the wave id as a proven-uniform (SGPR) value.
    const int split = __builtin_amdgcn_readfirstlane(wave);

    // Load / compute the 4 per-lane query positions.
    float axq[QPL], ayq[QPL], azq[QPL], a2q[QPL];
    if (FUSE) {
        float v = bmax_in[(b << 5) + (lane & 31)];
        #pragma unroll
        for (int o = 32; o > 0; o >>= 1) v = fmaxf(v, __shfl_down(v, o, 64));
        const float maxv = __shfl(v, 0, 64);
        #pragma unroll
        for (int j = 0; j < QPL; ++j) {
            const int t = (qb << 8) + (j << 6) + lane;
            const float md = md_in[t];
            const int   id = idx_in[t];
            const float alpha = BASE_ALPHA * (2.0f - md / (maxv + EPS));
            const float4 nb = near4[((size_t)b << 11) + id];
            const float* p = src + 3u * (unsigned)t;
            const float px = p[0], py = p[1], pz = p[2];
            axq[j] = fmaf(alpha, nb.x - px, px);
            ayq[j] = fmaf(alpha, nb.y - py, py);
            azq[j] = fmaf(alpha, nb.z - pz, pz);
            if (split == 0) {               // one copy of refined-1 to ws
                float* o = refined_out + 3u * (unsigned)t;
                o[0] = axq[j]; o[1] = ayq[j]; o[2] = azq[j];
            }
        }
    } else {
        #pragma unroll
        for (int j = 0; j < QPL; ++j) {
            const int t = (qb << 8) + (j << 6) + lane;
            const float* p = src + 3u * (unsigned)t;
            axq[j] = p[0]; ayq[j] = p[1]; azq[j] = p[2];
        }
    }
    #pragma unroll
    for (int j = 0; j < QPL; ++j)
        a2q[j] = fmaf(axq[j], axq[j], fmaf(ayq[j], ayq[j], azq[j] * azq[j]));

    // This wave's 32 groups, one s_load_dwordx16 each.
    const fx16* gq = (const fx16*)(ppg + ((size_t)b << 11) + ((size_t)split << 7));

    float best[QPL]; int bg[QPL];
    #pragma unroll
    for (int j = 0; j < QPL; ++j) { best[j] = 1e30f; bg[j] = 0; }

    #pragma unroll 1
    for (int ii = 0; ii < GPS; ii += 2) {
        fx16 A, B;
        // Two groups in flight. Early-clobber so neither dst aliases the addr.
        asm volatile("s_load_dwordx16 %0, %2, 0\n\t"
                     "s_load_dwordx16 %1, %2, 64"
                     : "=&s"(A), "=&s"(B)
                     : "s"(gq + ii));
        // Data-dependence-carrying wait: consumers of A/B cannot be hoisted.
        asm volatile("s_waitcnt lgkmcnt(0)" : "+s"(A), "+s"(B));

        #pragma unroll
        for (int j = 0; j < QPL; ++j) {
            const float ax = axq[j], ay = ayq[j], az = azq[j];
            const float d0 = fmaf(A[8],  az, fmaf(A[4], ay, A[0] * ax)) + A[12];
            const float d1 = fmaf(A[9],  az, fmaf(A[5], ay, A[1] * ax)) + A[13];
            const float d2 = fmaf(A[10], az, fmaf(A[6], ay, A[2] * ax)) + A[14];
            const float d3 = fmaf(A[11], az, fmaf(A[7], ay, A[3] * ax)) + A[15];
            const float gm = fminf(fminf(fminf(d0, d1), d2), d3);
            if (gm < best[j]) bg[j] = ii;          // strict <: earliest group wins
            best[j] = fminf(best[j], gm);
        }
        #pragma unroll
        for (int j = 0; j < QPL; ++j) {
            const float ax = axq[j], ay = ayq[j], az = azq[j];
            const float d0 = fmaf(B[8],  az, fmaf(B[4], ay, B[0] * ax)) + B[12];
            const float d1 = fmaf(B[9],  az, fmaf(B[5], ay, B[1] * ax)) + B[13];
            const float d2 = fmaf(B[10], az, fmaf(B[6], ay, B[2] * ax)) + B[14];
            const float d3 = fmaf(B[11], az, fmaf(B[7], ay, B[3] * ax)) + B[15];
            const float gm = fminf(fminf(fminf(d0, d1), d2), d3);
            if (gm < best[j]) bg[j] = ii + 1;
            best[j] = fminf(best[j], gm);
        }
    }

    // Epilogue: recover element index within the winning group (bit-exact
    // recompute from the same bytes in ppg; fminf returns one operand exactly,
    // so an equality must hit).
    const float4* wpg = ppg + ((size_t)b << 11) + ((size_t)split << 7);
    unsigned long long key[QPL];
    #pragma unroll
    for (int j = 0; j < QPL; ++j) {
        const int gi = bg[j];
        const float4 X = wpg[4 * gi + 0];
        const float4 Y = wpg[4 * gi + 1];
        const float4 Z = wpg[4 * gi + 2];
        const float4 W = wpg[4 * gi + 3];
        const float ax = axq[j], ay = ayq[j], az = azq[j];
        const float d0 = fmaf(Z.x, az, fmaf(Y.x, ay, X.x * ax)) + W.x;
        const float d1 = fmaf(Z.y, az, fmaf(Y.y, ay, X.y * ax)) + W.y;
        const float d2 = fmaf(Z.z, az, fmaf(Y.z, ay, X.z * ax)) + W.z;
        const float bv = best[j];
        int c;
        if      (d0 == bv) c = 0;
        else if (d1 == bv) c = 1;
        else if (d2 == bv) c = 2;
        else               c = 3;
        const int m = (split << 7) + (gi << 2) + c;   // index within batch
        const float dd = fmaxf(bv + a2q[j], 0.0f);    // nonneg -> uint-ordered
        key[j] = ((unsigned long long)__float_as_uint(dd) << 32) | (unsigned)m;
    }

    #pragma unroll
    for (int j = 0; j < QPL; ++j)
        lk[split * QPB + (j << 6) + lane] = key[j];
    __syncthreads();

    // Cross-split merge: u64 min == lexicographic (d^2, first index).
    if (wave < 4) {
        const int q2 = (wave << 6) + lane;   // 0..255
        unsigned long long kk = lk[q2];
        #pragma unroll
        for (int s = 1; s < SPLIT; ++s) {
            const unsigned long long k = lk[s * QPB + q2];
            if (k < kk) kk = k;
        }
        const float md = sqrtf(__uint_as_float((unsigned)(kk >> 32)));
        const int t2 = (qb << 8) + q2;
        md_out[t2]  = md;
        idx_out[t2] = (int)(kk & 0xffffffffu);
        float w = md;
        #pragma unroll
        for (int o = 32; o > 0; o >>= 1) w = fmaxf(w, __shfl_down(w, o, 64));
        if (lane == 0) smax[wave] = w;
    }
    __syncthreads();
    if (tid == 0)
        bmax_out[qb] = fmaxf(fmaxf(smax[0], smax[1]), fmaxf(smax[2], smax[3]));
}

// Final blend: out = refined1 + alpha2*(nearest2 - refined1).
__global__ __launch_bounds__(256) void update_kernel(
    const float* __restrict__ refined1,
    const float4* __restrict__ near4,
    const float* __restrict__ md2,
    const int*   __restrict__ idx2,
    const float* __restrict__ bmax2,   // [NBLK]
    float* __restrict__ out)
{
    const int t = blockIdx.x * 256 + threadIdx.x;
    const int b = t >> 13;
    const int lane = threadIdx.x & 63;
    float v = bmax2[(b << 5) + (lane & 31)];
    #pragma unroll
    for (int o = 32; o > 0; o >>= 1) v = fmaxf(v, __shfl_down(v, o, 64));
    const float maxv = __shfl(v, 0, 64);
    const float md = md2[t];
    const int   id = idx2[t];
    const float alpha = BASE_ALPHA * (2.0f - md / (maxv + EPS));
    const float4 nb = near4[((size_t)b << 11) + id];
    const float* p = refined1 + 3u * (unsigned)t;
    const float px = p[0], py = p[1], pz = p[2];
    float* o = out + 3u * (unsigned)t;
    o[0] = fmaf(alpha, nb.x - px, px);
    o[1] = fmaf(alpha, nb.y - py, py);
    o[2] = fmaf(alpha, nb.z - pz, pz);
}

extern "C" void kernel_launch(void* const* d_in, const int* in_sizes, int n_in,
                              void* d_out, int out_size, void* d_ws, size_t ws_size,
                              hipStream_t stream) {
    const float* pred    = (const float*)d_in[0];   // [8,8192,3] fp32
    const float* partial = (const float*)d_in[1];   // [8,2048,3] fp32
    float* out = (float*)d_out;

    char* ws = (char*)d_ws;                          // 16B-aligned chunks first
    float4* ppg   = (float4*)ws;                     // 256 KB grouped-SoA P'
    float4* near4 = (float4*)(ws + 262144);          // 256 KB
    float*  ref1  = (float*)(ws + 524288);           // 768 KB
    float*  md1   = (float*)(ws + 1310720);          // 256 KB
    int*    idx1  = (int*)(ws + 1572864);            // 256 KB
    float*  bmax1 = (float*)(ws + 1835008);          // 1 KB
    float*  bmax2 = bmax1 + NBLK;                    // 1 KB

    prep_kernel<<<MTOT / 256, 256, 0, stream>>>(partial, (float*)ppg, near4);

    // Iter 1 NN: pred -> md1/idx1/bmax1
    nn_kernel<false><<<NBLK, 1024, 0, stream>>>(
        pred, ppg, near4, nullptr, nullptr, nullptr, nullptr, md1, idx1, bmax1);

    // Iter 1 update fused into iter 2 NN: writes ref1, overwrites md1/idx1.
    nn_kernel<true><<<NBLK, 1024, 0, stream>>>(
        pred, ppg, near4, md1, idx1, bmax1, ref1, md1, idx1, bmax2);

    // Iter 2 update: ref1 -> out
    update_kernel<<<NPTS / 256, 256, 0, stream>>>(ref1, near4, md1, idx1, bmax2, out);
}